// Round 3
// baseline (195.148 us; speedup 1.0000x reference)
//
#include <hip/hip_runtime.h>
#include <hip/hip_fp8.h>

typedef __attribute__((ext_vector_type(8))) short short8;
typedef __attribute__((ext_vector_type(4))) float f32x4;
typedef __attribute__((ext_vector_type(16))) float f32x16;
typedef __attribute__((ext_vector_type(4))) int i32x4;
typedef __attribute__((ext_vector_type(8))) int i32x8;

// async global->LDS, 16B per lane, dest = wave-uniform base + lane*16
#define GLOAD16(g, l)                                                        \
  __builtin_amdgcn_global_load_lds(                                          \
      (const __attribute__((address_space(1))) unsigned int*)(g),            \
      (__attribute__((address_space(3))) unsigned int*)(l), 16, 0, 0)

__device__ __forceinline__ unsigned short f2bf(float f) {
  union { float f; unsigned int u; } v;
  v.f = f;
  unsigned int u = v.u;
  u += 0x7FFFu + ((u >> 16) & 1u);  // round-to-nearest-even
  return (unsigned short)(u >> 16);
}

__device__ __forceinline__ short8 pack8(float4 a, float4 b) {
  short8 r;
  r[0] = (short)f2bf(a.x); r[1] = (short)f2bf(a.y);
  r[2] = (short)f2bf(a.z); r[3] = (short)f2bf(a.w);
  r[4] = (short)f2bf(b.x); r[5] = (short)f2bf(b.y);
  r[6] = (short)f2bf(b.z); r[7] = (short)f2bf(b.w);
  return r;
}

__device__ __forceinline__ unsigned char f2e4m3(float x) {
  __hip_fp8_e4m3 t(x);  // OCP e4m3fn, HW cvt on gfx950
  return *reinterpret_cast<unsigned char*>(&t);
}

#define BM 128
#define BN 128
#define BK 32

// ---------- kernel 1a: prep for fp8 fast path (fp32 -> e4m3 + norms) -------
__global__ __launch_bounds__(256)
void prep_fp8_kernel(const float* __restrict__ emb, const int* __restrict__ labels,
                     const float* __restrict__ emb_mem, const int* __restrict__ lbl_mem,
                     unsigned char* __restrict__ refq, float* __restrict__ sqb,
                     int* __restrict__ reflab, float* __restrict__ facc,
                     int* __restrict__ fcnt, int Bn, int Dn, int Mn) {
  if (blockIdx.x == 0 && threadIdx.x == 0) { *facc = 0.f; *fcnt = 0; }
  int wid = threadIdx.x >> 6, lane = threadIdx.x & 63;
  int row = blockIdx.x * 4 + wid;
  if (row >= Mn) return;
  const float* src = (row < Bn) ? (emb + (size_t)row * Dn)
                                : (emb_mem + (size_t)(row - Bn) * Dn);
  unsigned char* dst = refq + (size_t)row * Dn;
  float s = 0.f;
  for (int c0 = lane * 8; c0 < Dn; c0 += 64 * 8) {
    float4 v0 = ((const float4*)(src + c0))[0];
    float4 v1 = ((const float4*)(src + c0))[1];
    s += v0.x * v0.x + v0.y * v0.y + v0.z * v0.z + v0.w * v0.w;
    s += v1.x * v1.x + v1.y * v1.y + v1.z * v1.z + v1.w * v1.w;
    unsigned long long p =
        (unsigned long long)f2e4m3(v0.x)        |
        ((unsigned long long)f2e4m3(v0.y) << 8) |
        ((unsigned long long)f2e4m3(v0.z) << 16)|
        ((unsigned long long)f2e4m3(v0.w) << 24)|
        ((unsigned long long)f2e4m3(v1.x) << 32)|
        ((unsigned long long)f2e4m3(v1.y) << 40)|
        ((unsigned long long)f2e4m3(v1.z) << 48)|
        ((unsigned long long)f2e4m3(v1.w) << 56);
    *(unsigned long long*)(dst + c0) = p;
  }
#pragma unroll
  for (int off = 32; off; off >>= 1) s += __shfl_xor(s, off);
  if (lane == 0) {
    sqb[row] = s;
    reflab[row] = (row < Bn) ? labels[row] : lbl_mem[row - Bn];
  }
}

// ---------- kernel 2a: MX-scaled fp8 GEMM, 128x128 tile, full-K in LDS -----
// Round-2 lesson: per-phase barrier+drain overhead (~3Kcy) drowned the 68cy
// of MFMA per wave per phase -> MfmaUtil 8%. Fix: K=512B fits in LDS whole.
// Stage full A-tile (64KB) + B-tile (64KB) = 128KB LDS, 1 block/CU, issued
// quarter-major (8 GLOADs/wave/quarter); compute quarter q after
// s_waitcnt vmcnt(24-8q) + raw s_barrier. Quarters are DISJOINT LDS ->
// counted vmcnt has zero overwrite hazard. Only quarter-0 latency exposed.
// LDS layout per operand: [4 quarters][128 rows][128B]; slot (16B) swizzle
// slot_phys = slot_log ^ (row&7), applied via pre-swizzled global source
// (linear global_load_lds dest) + same XOR on ds_read (both-sides).
// Frag reads: 8 lanes per 16B slot, uniform over 32 banks -> conflict-free.
__global__ __launch_bounds__(256, 1)
void gemm_mxf8_kernel(const unsigned char* __restrict__ refq,
                      const float* __restrict__ sqb,
                      const int* __restrict__ reflab,
                      float* __restrict__ part) {
  __shared__ __align__(16) char smem[131072];
  char* Asm = smem;            // [4][128][128] quarter-major
  char* Bsm = smem + 65536;
  f32x4* red4 = (f32x4*)smem;  // epilogue aliases first 32KB (A q0/q1, dead)

  const int npart = 256;               // col tiles (128 wide)
  int bid = blockIdx.x;                // 2048 blocks
  int cx = bid & 7, g = bid >> 3;      // XCD-sliced: XCD cx owns col slab
  int jt = cx * 32 + (g >> 3);         // col tile [0,256)
  int it = g & 7;                      // row tile [0,8)
  int rowBase = it * 128, colBase = jt * 128;

  int tid = threadIdx.x, lane = tid & 63, w = tid >> 6;
  int wr = w >> 1, wc = w & 1;         // 2x2 waves; each 64 rows x 64 cols
  int c32 = lane & 31, hi = lane >> 5;

  // staging source (pre-swizzled): lane -> row lane>>3 (of 8), slot lane&7
  int sr = lane >> 3, sj = lane & 7;   // sr in [0,8): row&7 == sr
  const char* gA = (const char*)refq + (size_t)(rowBase + w * 32 + sr) * 512
                   + ((sj ^ sr) << 4);
  const char* gB = (const char*)refq + (size_t)(colBase + w * 32 + sr) * 512
                   + ((sj ^ sr) << 4);

  // issue ALL 32 GLOADs per wave, quarter-major (vmcnt counts this order)
#pragma unroll
  for (int q = 0; q < 4; ++q) {
#pragma unroll
    for (int i = 0; i < 4; ++i) {      // i = 8-row group within wave's 32 rows
      GLOAD16(gA + (size_t)i * 4096 + q * 128,
              Asm + q * 16384 + w * 4096 + i * 1024);
      GLOAD16(gB + (size_t)i * 4096 + q * 128,
              Bsm + q * 16384 + w * 4096 + i * 1024);
    }
    __builtin_amdgcn_sched_barrier(0);  // pin quarter issue-order
  }

  f32x16 acc[2][2] = {};
#pragma unroll
  for (int q = 0; q < 4; ++q) {
    if (q == 0)      asm volatile("s_waitcnt vmcnt(24)" ::: "memory");
    else if (q == 1) asm volatile("s_waitcnt vmcnt(16)" ::: "memory");
    else if (q == 2) asm volatile("s_waitcnt vmcnt(8)" ::: "memory");
    else             asm volatile("s_waitcnt vmcnt(0)" ::: "memory");
    __builtin_amdgcn_s_barrier();       // all waves' quarter-q loads landed
    __builtin_amdgcn_sched_barrier(0);
#pragma unroll
    for (int s = 0; s < 2; ++s) {       // chunk k = 2q+s (64B of K)
      i32x8 af[2], bf[2];
#pragma unroll
      for (int mi = 0; mi < 2; ++mi) {
        int r = wr * 64 + mi * 32 + c32;
        const char* p = Asm + q * 16384 + r * 128;
        int s0 = (4 * s + 2 * hi) ^ (r & 7);
        int s1 = (4 * s + 2 * hi + 1) ^ (r & 7);
        i32x4 lo = *(const i32x4*)(p + (s0 << 4));
        i32x4 h4 = *(const i32x4*)(p + (s1 << 4));
        af[mi] = __builtin_shufflevector(lo, h4, 0, 1, 2, 3, 4, 5, 6, 7);
      }
#pragma unroll
      for (int ni = 0; ni < 2; ++ni) {
        int r = wc * 64 + ni * 32 + c32;
        const char* p = Bsm + q * 16384 + r * 128;
        int s0 = (4 * s + 2 * hi) ^ (r & 7);
        int s1 = (4 * s + 2 * hi + 1) ^ (r & 7);
        i32x4 lo = *(const i32x4*)(p + (s0 << 4));
        i32x4 h4 = *(const i32x4*)(p + (s1 << 4));
        bf[ni] = __builtin_shufflevector(lo, h4, 0, 1, 2, 3, 4, 5, 6, 7);
      }
#pragma unroll
      for (int mi = 0; mi < 2; ++mi)
#pragma unroll
        for (int ni = 0; ni < 2; ++ni)
          acc[mi][ni] = __builtin_amdgcn_mfma_scale_f32_32x32x64_f8f6f4(
              af[mi], bf[ni], acc[mi][ni],
              0, 0,                       // cbsz=fp8(e4m3), blgp=fp8(e4m3)
              0, 0x7F7F7F7F,              // opselA, scaleA (all bytes = 1.0)
              0, 0x7F7F7F7F);             // opselB, scaleB
    }
  }
  __syncthreads();  // all frag ds_reads done before red4 aliases LDS

  // ---- epilogue: 32x32 C-layout: col=lane&31, row=(reg&3)+8*(reg>>2)+4*hi
  float sqc[2];
  int labc[2];
#pragma unroll
  for (int ni = 0; ni < 2; ++ni) {
    int gcol = colBase + wc * 64 + ni * 32 + c32;
    sqc[ni] = sqb[gcol];
    labc[ni] = reflab[gcol];
  }
#pragma unroll
  for (int mi = 0; mi < 2; ++mi) {
#pragma unroll
    for (int reg = 0; reg < 16; ++reg) {
      int rl = wr * 64 + mi * 32 + (reg & 3) + 8 * (reg >> 2) + 4 * hi;
      int grow = rowBase + rl;
      float sqr = sqb[grow];
      int labr = reflab[grow];
      float ps = 0.f, ns = 0.f, cpk = 0.f;  // cpk = pos_cnt + 512*neg_cnt
#pragma unroll
      for (int ni = 0; ni < 2; ++ni) {
        int gcol = colBase + wc * 64 + ni * 32 + c32;
        float dist = fmaxf(sqr + sqc[ni] - 2.0f * acc[mi][ni][reg], 0.f);
        bool self = (gcol == grow);  // idx_ref[j]!=i reduces to j!=i
        bool same = (labc[ni] == labr);
        if (same && !self && dist > 0.f) { ps += dist; cpk += 1.f; }
        if (!same && !self && dist < 1.f) { ns += 1.f - dist; cpk += 512.f; }
      }
      // reduce over 32 cols (lane&31); xor16+xor8 -> lanes c32<8 hold partials
      ps += __shfl_xor(ps, 16); ns += __shfl_xor(ns, 16); cpk += __shfl_xor(cpk, 16);
      ps += __shfl_xor(ps, 8);  ns += __shfl_xor(ns, 8);  cpk += __shfl_xor(cpk, 8);
      if (c32 < 8) {
        f32x4 v = {ps, ns, cpk, 0.f};
        red4[(wc * 128 + rl) * 8 + c32] = v;
      }
    }
  }
  __syncthreads();
  if (tid < 128) {
    f32x4 s = {0.f, 0.f, 0.f, 0.f};
#pragma unroll
    for (int c2 = 0; c2 < 2; ++c2)
#pragma unroll
      for (int k = 0; k < 8; ++k)  // (k+tid)&7: lanes sweep all 32 banks
        s += red4[(c2 * 128 + tid) * 8 + ((k + tid) & 7)];
    float nc = floorf(s[2] * (1.0f / 512.0f));
    float pc = s[2] - 512.f * nc;
    f32x4 o = {s[0], pc, s[1], nc};
    ((f32x4*)part)[(size_t)(rowBase + tid) * npart + jt] = o;  // [row][jt]
  }
}

// ---------- fallback path (generic shapes): bf16 prep + generic GEMM -------
__global__ __launch_bounds__(256)
void prep2_kernel(const float* __restrict__ emb, const int* __restrict__ labels,
                  const float* __restrict__ emb_mem, const int* __restrict__ lbl_mem,
                  unsigned short* __restrict__ refbf, float* __restrict__ sqb,
                  int* __restrict__ reflab, float* __restrict__ facc,
                  int* __restrict__ fcnt, int Bn, int Dn, int Mn) {
  if (blockIdx.x == 0 && threadIdx.x == 0) { *facc = 0.f; *fcnt = 0; }
  int wid = threadIdx.x >> 6, lane = threadIdx.x & 63;
  int row = blockIdx.x * 4 + wid;
  if (row >= Mn) return;
  const float* src = (row < Bn) ? (emb + (size_t)row * Dn)
                                : (emb_mem + (size_t)(row - Bn) * Dn);
  unsigned short* dst = refbf + (size_t)row * Dn;
  float s = 0.f;
  for (int c0 = lane * 8; c0 < Dn; c0 += 64 * 8) {
    float4 v0 = ((const float4*)(src + c0))[0];
    float4 v1 = ((const float4*)(src + c0))[1];
    s += v0.x * v0.x + v0.y * v0.y + v0.z * v0.z + v0.w * v0.w;
    s += v1.x * v1.x + v1.y * v1.y + v1.z * v1.z + v1.w * v1.w;
    *(short8*)(dst + c0) = pack8(v0, v1);
  }
#pragma unroll
  for (int off = 32; off; off >>= 1) s += __shfl_xor(s, off);
  if (lane == 0) {
    sqb[row] = s;
    reflab[row] = (row < Bn) ? labels[row] : lbl_mem[row - Bn];
  }
}

__global__ __launch_bounds__(256)
void gemm_generic_kernel(const unsigned short* __restrict__ refbf,
                         const float* __restrict__ sqb,
                         const int* __restrict__ reflab,
                         float* __restrict__ part,
                         int Dn, int mtiles, int ntiles) {
  __shared__ unsigned short As[BM * BK];
  __shared__ unsigned short Bs[BN * BK];
  __shared__ f32x4 redbuf4[2 * BM];

  int bid = blockIdx.x;
  int it = bid % mtiles, jt = bid / mtiles;
  int rowBase = it * BM, colBase = jt * BN;
  int tid = threadIdx.x, lane = tid & 63, w = tid >> 6;
  int wr = w >> 1, wc = w & 1;
  int l16 = lane & 15, quad = lane >> 4;
  int lrow = lane >> 2, lk = lane & 3;
  size_t rowB = (size_t)Dn * 2;
  int r0 = w * 32 + lrow;
  int ca = (lk - (r0 >> 1)) & 3;
  const char* gA0 = (const char*)refbf + (size_t)(rowBase + r0) * rowB + ca * 16;
  const char* gA1 = gA0 + 16 * rowB;
  const char* gB0 = (const char*)refbf + (size_t)(colBase + r0) * rowB + ca * 16;
  const char* gB1 = gB0 + 16 * rowB;
  char* lA = (char*)As + w * 2048;
  char* lB = (char*)Bs + w * 2048;

  f32x4 acc[4][4] = {};
  for (int k0 = 0; k0 < Dn; k0 += BK) {
    int koff = k0 * 2;
    GLOAD16(gA0 + koff, lA);
    GLOAD16(gA1 + koff, lA + 1024);
    GLOAD16(gB0 + koff, lB);
    GLOAD16(gB1 + koff, lB + 1024);
    __syncthreads();
    short8 af[4], bfr[4];
#pragma unroll
    for (int mi = 0; mi < 4; ++mi) {
      int row = wr * 64 + mi * 16 + l16;
      af[mi] = *(const short8*)&As[row * BK + ((quad + (row >> 1)) & 3) * 8];
    }
#pragma unroll
    for (int ni = 0; ni < 4; ++ni) {
      int row = wc * 64 + ni * 16 + l16;
      bfr[ni] = *(const short8*)&Bs[row * BK + ((quad + (row >> 1)) & 3) * 8];
    }
#pragma unroll
    for (int mi = 0; mi < 4; ++mi)
#pragma unroll
      for (int ni = 0; ni < 4; ++ni)
        acc[mi][ni] = __builtin_amdgcn_mfma_f32_16x16x32_bf16(
            af[mi], bfr[ni], acc[mi][ni], 0, 0, 0);
    __syncthreads();
  }

  float sqc[4];
  int labc[4];
#pragma unroll
  for (int ni = 0; ni < 4; ++ni) {
    int gcol = colBase + wc * 64 + ni * 16 + l16;
    sqc[ni] = sqb[gcol];
    labc[ni] = reflab[gcol];
  }
#pragma unroll
  for (int mi = 0; mi < 4; ++mi) {
    int lr0 = wr * 64 + mi * 16 + quad * 4;
#pragma unroll
    for (int r = 0; r < 4; ++r) {
      int lrl = lr0 + r;
      int grow = rowBase + lrl;
      float sqr = sqb[grow];
      int labr = reflab[grow];
      float ps = 0.f, pc = 0.f, ns = 0.f, nc = 0.f;
#pragma unroll
      for (int ni = 0; ni < 4; ++ni) {
        int gcol = colBase + wc * 64 + ni * 16 + l16;
        float dist = fmaxf(sqr + sqc[ni] - 2.0f * acc[mi][ni][r], 0.f);
        bool self = (gcol == grow);
        bool same = (labc[ni] == labr);
        if (same && !self && dist > 0.f) { ps += dist; pc += 1.f; }
        if (!same && !self && dist < 1.f) { ns += 1.f - dist; nc += 1.f; }
      }
#pragma unroll
      for (int off = 8; off; off >>= 1) {
        ps += __shfl_xor(ps, off);
        pc += __shfl_xor(pc, off);
        ns += __shfl_xor(ns, off);
        nc += __shfl_xor(nc, off);
      }
      if (l16 == 0) {
        f32x4 v = {ps, pc, ns, nc};
        redbuf4[wc * BM + lrl] = v;
      }
    }
  }
  __syncthreads();
  if (tid < BM) {
    f32x4 s = redbuf4[tid] + redbuf4[BM + tid];
    ((f32x4*)part)[(size_t)(rowBase + tid) * ntiles + jt] = s;
  }
}

// ---------- kernel 3: per-row fold + global sum (atomic + ticket) ----------
__global__ __launch_bounds__(256)
void reduce_final_kernel(const float* __restrict__ part,
                         float* __restrict__ facc, int* __restrict__ fcnt,
                         float* __restrict__ out, int Bn, int npart) {
  __shared__ float rsum[4];
  int tid = threadIdx.x, w = tid >> 6, lane = tid & 63;
  int row = blockIdx.x * 4 + w;
  const f32x4* part4 = (const f32x4*)part;
  float rl = 0.f;
  if (row < Bn) {
    f32x4 a = {0.f, 0.f, 0.f, 0.f};
    for (int j = lane; j < npart; j += 64)
      a += part4[(size_t)row * npart + j];
#pragma unroll
    for (int off = 32; off; off >>= 1) {
      a[0] += __shfl_xor(a[0], off);
      a[1] += __shfl_xor(a[1], off);
      a[2] += __shfl_xor(a[2], off);
      a[3] += __shfl_xor(a[3], off);
    }
    rl = a[0] / (a[1] + 1e-6f) + a[2] / (a[3] + 1e-6f);
  }
  if (lane == 0) rsum[w] = rl;
  __syncthreads();
  if (tid == 0) {
    float bs = rsum[0] + rsum[1] + rsum[2] + rsum[3];
    atomicAdd(facc, bs);
    __threadfence();
    int old = atomicAdd(fcnt, 1);
    if (old == (int)gridDim.x - 1) {
      __threadfence();
      float tot = atomicAdd(facc, 0.f);
      out[0] = tot / (float)Bn;
    }
  }
}

// ---------- host ----------
extern "C" void kernel_launch(void* const* d_in, const int* in_sizes, int n_in,
                              void* d_out, int out_size, void* d_ws, size_t ws_size,
                              hipStream_t stream) {
  const float* emb     = (const float*)d_in[0];
  const int*   labels  = (const int*)d_in[1];
  const float* emb_mem = (const float*)d_in[2];
  const int*   lbl_mem = (const int*)d_in[3];
  // d_in[4] (add_to_mem) does not affect the returned loss.

  int Bn = in_sizes[1];
  int Dn = in_sizes[0] / Bn;
  int Rn = in_sizes[3];
  int Mn = Bn + Rn;
  int mtiles = Bn / BM, ntiles = Mn / BN;

  char* ws = (char*)d_ws;
  unsigned char*  refq  = (unsigned char*)ws;                  // Mn*Dn fp8 (fast)
  unsigned short* refbf = (unsigned short*)ws;                 // Mn*Dn bf16 (generic)
  size_t off = (size_t)Mn * Dn * 2;                            // sized for bf16
  float* sqb    = (float*)(ws + off);                          // Mn
  int*   reflab = (int*)(ws + off + (size_t)Mn * 4);           // Mn
  float* part   = (float*)(ws + off + (size_t)Mn * 8);         // Bn*ntiles*4
  float* facc   = part + (size_t)Bn * ntiles * 4;              // 1
  int*   fcnt   = (int*)(facc + 1);                            // 1

  bool fast = (Dn == 512 && mtiles == 8 && ntiles == 256);
  if (fast) {
    prep_fp8_kernel<<<(Mn + 3) / 4, 256, 0, stream>>>(
        emb, labels, emb_mem, lbl_mem, refq, sqb, reflab, facc, fcnt, Bn, Dn, Mn);
    gemm_mxf8_kernel<<<2048, 256, 0, stream>>>(refq, sqb, reflab, part);
    reduce_final_kernel<<<(Bn + 3) / 4, 256, 0, stream>>>(
        part, facc, fcnt, (float*)d_out, Bn, 256);
  } else {
    prep2_kernel<<<(Mn + 3) / 4, 256, 0, stream>>>(
        emb, labels, emb_mem, lbl_mem, refbf, sqb, reflab, facc, fcnt, Bn, Dn, Mn);
    gemm_generic_kernel<<<mtiles * ntiles, 256, 0, stream>>>(
        refbf, sqb, reflab, part, Dn, mtiles, ntiles);
    reduce_final_kernel<<<(Bn + 3) / 4, 256, 0, stream>>>(
        part, facc, fcnt, (float*)d_out, Bn, ntiles);
  }
}

// Round 4
// 158.839 us; speedup vs baseline: 1.2286x; 1.2286x over previous
//
#include <hip/hip_runtime.h>
#include <hip/hip_fp8.h>

typedef __attribute__((ext_vector_type(8))) short short8;
typedef __attribute__((ext_vector_type(4))) float f32x4;

// async global->LDS, 16B per lane, dest = wave-uniform base + lane*16
#define GLOAD16(g, l)                                                        \
  __builtin_amdgcn_global_load_lds(                                          \
      (const __attribute__((address_space(1))) unsigned int*)(g),            \
      (__attribute__((address_space(3))) unsigned int*)(l), 16, 0, 0)

__device__ __forceinline__ unsigned short f2bf(float f) {
  union { float f; unsigned int u; } v;
  v.f = f;
  unsigned int u = v.u;
  u += 0x7FFFu + ((u >> 16) & 1u);  // round-to-nearest-even
  return (unsigned short)(u >> 16);
}

__device__ __forceinline__ short8 pack8(float4 a, float4 b) {
  short8 r;
  r[0] = (short)f2bf(a.x); r[1] = (short)f2bf(a.y);
  r[2] = (short)f2bf(a.z); r[3] = (short)f2bf(a.w);
  r[4] = (short)f2bf(b.x); r[5] = (short)f2bf(b.y);
  r[6] = (short)f2bf(b.z); r[7] = (short)f2bf(b.w);
  return r;
}

__device__ __forceinline__ unsigned char f2e4m3(float x) {
  __hip_fp8_e4m3 t(x);  // OCP e4m3fn, HW cvt on gfx950
  return *reinterpret_cast<unsigned char*>(&t);
}

#define BM 128
#define BN 128
#define BK 32

// ---------- kernel 1a: prep for fp8 fast path (fp32 -> e4m3 + norms) -------
// Round-4: consolidated 8192 -> 2048 blocks; each wave handles 4 rows
// (unrolled -> 4 independent load chains pipelined). Same math/coalescing.
__global__ __launch_bounds__(256)
void prep_fp8_kernel(const float* __restrict__ emb, const int* __restrict__ labels,
                     const float* __restrict__ emb_mem, const int* __restrict__ lbl_mem,
                     unsigned char* __restrict__ refq, float* __restrict__ sqb,
                     int* __restrict__ reflab, float* __restrict__ facc,
                     int* __restrict__ fcnt, int Bn, int Dn, int Mn) {
  if (blockIdx.x == 0 && threadIdx.x == 0) { *facc = 0.f; *fcnt = 0; }
  int wid = threadIdx.x >> 6, lane = threadIdx.x & 63;
  int row0 = blockIdx.x * 16 + wid * 4;
#pragma unroll
  for (int rr = 0; rr < 4; ++rr) {
    int row = row0 + rr;
    if (row >= Mn) continue;
    const float* src = (row < Bn) ? (emb + (size_t)row * Dn)
                                  : (emb_mem + (size_t)(row - Bn) * Dn);
    unsigned char* dst = refq + (size_t)row * Dn;
    float s = 0.f;
    for (int c0 = lane * 8; c0 < Dn; c0 += 64 * 8) {
      float4 v0 = ((const float4*)(src + c0))[0];
      float4 v1 = ((const float4*)(src + c0))[1];
      s += v0.x * v0.x + v0.y * v0.y + v0.z * v0.z + v0.w * v0.w;
      s += v1.x * v1.x + v1.y * v1.y + v1.z * v1.z + v1.w * v1.w;
      unsigned long long p =
          (unsigned long long)f2e4m3(v0.x)        |
          ((unsigned long long)f2e4m3(v0.y) << 8) |
          ((unsigned long long)f2e4m3(v0.z) << 16)|
          ((unsigned long long)f2e4m3(v0.w) << 24)|
          ((unsigned long long)f2e4m3(v1.x) << 32)|
          ((unsigned long long)f2e4m3(v1.y) << 40)|
          ((unsigned long long)f2e4m3(v1.z) << 48)|
          ((unsigned long long)f2e4m3(v1.w) << 56);
      *(unsigned long long*)(dst + c0) = p;
    }
#pragma unroll
    for (int off = 32; off; off >>= 1) s += __shfl_xor(s, off);
    if (lane == 0) {
      sqb[row] = s;
      reflab[row] = (row < Bn) ? labels[row] : lbl_mem[row - Bn];
    }
  }
}

// ---------- kernel 2a: fp8 GEMM 128x256, r8 two-barrier structure ----------
// RESTORED round-0 kernel verbatim (validated 53us, MfmaUtil 24%, VGPR 88 —
// acc in AGPRs via non-scaled fp8 MFMA; mfma_scale variants do NOT get AGPR
// allocation (rounds 1-3: VGPR 128-144/spill, 82-87us). Keep this structure.
// BK=32 fp8 = 32B/row: A-tile 4KB, B-tile 8KB.
// Per wave per iter: 3 GLOAD16, 12 ds_read_b64, 32 MFMAs.
// Chunk rotation cL=(lane&1)^((lane>>3)&1) makes b64 reads <=2-way (free).
__global__ __launch_bounds__(256, 2)
void gemm512x2f8_kernel(const unsigned char* __restrict__ refq,
                        const float* __restrict__ sqb,
                        const int* __restrict__ reflab,
                        float* __restrict__ part) {
  // 32KB: staging uses [As 4K | Bs 8K]; epilogue red4 aliases all 32KB
  __shared__ __align__(16) char smem[32768];
  char* As = smem;
  char* Bs = smem + 4096;
  f32x4* red4 = (f32x4*)smem;  // [2][128][8] f32x4

  const int npart = 128;               // j-pairs
  int bid = blockIdx.x;                // 1024 blocks
  int c = bid & 7, g = bid >> 3;       // XCD-sliced (validated r3/r5)
  int jp = c * 16 + (g >> 3);          // j-pair index [0,128)
  int it = g & 7;
  int rowBase = it * BM, colBase = jp * 256;

  int tid = threadIdx.x, lane = tid & 63, w = tid >> 6;
  int wr = w >> 1, wc = w & 1;         // 2x2 waves; each 64 rows x 128 cols
  int l16 = lane & 15, quad = lane >> 4;

  // staging: 2 lanes per 32B tile-row; physical chunk (lane&1) holds logical
  // chunk cL = (lane&1) ^ ((row>>2)&1) -> read-side bank spread <=2-way
  int lrow = lane >> 1;
  int cL = (lane & 1) ^ ((lane >> 3) & 1);
  const char* gA0 = (const char*)refq + (size_t)(rowBase + w * 32 + lrow) * 512 + cL * 16;
  const char* gB0 = (const char*)refq + (size_t)(colBase + w * 64 + lrow) * 512 + cL * 16;
  const char* gB1 = gB0 + 32 * 512;
  char* lA = As + w * 1024;
  char* lB = Bs + w * 2048;

  f32x4 acc[4][8] = {};
  for (int kk = 0; kk < 16; ++kk) {
    int ko = kk * 32;
    GLOAD16(gA0 + ko, lA);
    GLOAD16(gB0 + ko, lB);
    GLOAD16(gB1 + ko, lB + 1024);
    __syncthreads();
    long af[4], bfr[8];
#pragma unroll
    for (int mi = 0; mi < 4; ++mi) {
      int row = wr * 64 + mi * 16 + l16;
      int off = row * 32 + ((((quad >> 1) ^ ((row >> 2) & 1)) << 4)) + (quad & 1) * 8;
      af[mi] = *(const long*)(As + off);
    }
#pragma unroll
    for (int ni = 0; ni < 8; ++ni) {
      int row = wc * 128 + ni * 16 + l16;
      int off = row * 32 + ((((quad >> 1) ^ ((row >> 2) & 1)) << 4)) + (quad & 1) * 8;
      bfr[ni] = *(const long*)(Bs + off);
    }
#pragma unroll
    for (int mi = 0; mi < 4; ++mi)
#pragma unroll
      for (int ni = 0; ni < 8; ++ni)
        acc[mi][ni] = __builtin_amdgcn_mfma_f32_16x16x32_fp8_fp8(
            af[mi], bfr[ni], acc[mi][ni], 0, 0, 0);
    __syncthreads();
  }

  // ---- epilogue (r8-validated): packed counters, 1 shfl, LDS fold --------
  float sqc[8];
  int labc[8];
#pragma unroll
  for (int ni = 0; ni < 8; ++ni) {
    int gcol = colBase + wc * 128 + ni * 16 + l16;
    sqc[ni] = sqb[gcol];
    labc[ni] = reflab[gcol];
  }
#pragma unroll
  for (int mi = 0; mi < 4; ++mi) {
    int lr0 = wr * 64 + mi * 16 + quad * 4;
#pragma unroll
    for (int r = 0; r < 4; ++r) {
      int lrl = lr0 + r;
      int grow = rowBase + lrl;
      float sqr = sqb[grow];
      int labr = reflab[grow];
      float ps = 0.f, ns = 0.f, cpk = 0.f;  // cpk = pos_cnt + 512*neg_cnt
#pragma unroll
      for (int ni = 0; ni < 8; ++ni) {
        int gcol = colBase + wc * 128 + ni * 16 + l16;
        float dist = fmaxf(sqr + sqc[ni] - 2.0f * acc[mi][ni][r], 0.f);
        bool self = (gcol == grow);  // idx_ref[j]!=i reduces to j!=i
        bool same = (labc[ni] == labr);
        if (same && !self && dist > 0.f) { ps += dist; cpk += 1.f; }
        if (!same && !self && dist < 1.f) { ns += 1.f - dist; cpk += 512.f; }
      }
      ps += __shfl_xor(ps, 8);
      ns += __shfl_xor(ns, 8);
      cpk += __shfl_xor(cpk, 8);
      if (l16 < 8) {
        f32x4 v = {ps, ns, cpk, 0.f};
        red4[(wc * BM + lrl) * 8 + l16] = v;
      }
    }
  }
  __syncthreads();
  if (tid < BM) {
    f32x4 s = {0.f, 0.f, 0.f, 0.f};
#pragma unroll
    for (int c2 = 0; c2 < 2; ++c2)
#pragma unroll
      for (int k = 0; k < 8; ++k)  // (k+tid)&7: lanes sweep all 32 banks
        s += red4[(c2 * BM + tid) * 8 + ((k + tid) & 7)];
    float nc = floorf(s[2] * (1.0f / 512.0f));
    float pc = s[2] - 512.f * nc;
    f32x4 o = {s[0], pc, s[1], nc};
    ((f32x4*)part)[(size_t)(rowBase + tid) * npart + jp] = o;  // [row][jp]
  }
}

// ---------- fallback path (generic shapes): bf16 prep + generic GEMM -------
__global__ __launch_bounds__(256)
void prep2_kernel(const float* __restrict__ emb, const int* __restrict__ labels,
                  const float* __restrict__ emb_mem, const int* __restrict__ lbl_mem,
                  unsigned short* __restrict__ refbf, float* __restrict__ sqb,
                  int* __restrict__ reflab, float* __restrict__ facc,
                  int* __restrict__ fcnt, int Bn, int Dn, int Mn) {
  if (blockIdx.x == 0 && threadIdx.x == 0) { *facc = 0.f; *fcnt = 0; }
  int wid = threadIdx.x >> 6, lane = threadIdx.x & 63;
  int row = blockIdx.x * 4 + wid;
  if (row >= Mn) return;
  const float* src = (row < Bn) ? (emb + (size_t)row * Dn)
                                : (emb_mem + (size_t)(row - Bn) * Dn);
  unsigned short* dst = refbf + (size_t)row * Dn;
  float s = 0.f;
  for (int c0 = lane * 8; c0 < Dn; c0 += 64 * 8) {
    float4 v0 = ((const float4*)(src + c0))[0];
    float4 v1 = ((const float4*)(src + c0))[1];
    s += v0.x * v0.x + v0.y * v0.y + v0.z * v0.z + v0.w * v0.w;
    s += v1.x * v1.x + v1.y * v1.y + v1.z * v1.z + v1.w * v1.w;
    *(short8*)(dst + c0) = pack8(v0, v1);
  }
#pragma unroll
  for (int off = 32; off; off >>= 1) s += __shfl_xor(s, off);
  if (lane == 0) {
    sqb[row] = s;
    reflab[row] = (row < Bn) ? labels[row] : lbl_mem[row - Bn];
  }
}

__global__ __launch_bounds__(256)
void gemm_generic_kernel(const unsigned short* __restrict__ refbf,
                         const float* __restrict__ sqb,
                         const int* __restrict__ reflab,
                         float* __restrict__ part,
                         int Dn, int mtiles, int ntiles) {
  __shared__ unsigned short As[BM * BK];
  __shared__ unsigned short Bs[BN * BK];
  __shared__ f32x4 redbuf4[2 * BM];

  int bid = blockIdx.x;
  int it = bid % mtiles, jt = bid / mtiles;
  int rowBase = it * BM, colBase = jt * BN;
  int tid = threadIdx.x, lane = tid & 63, w = tid >> 6;
  int wr = w >> 1, wc = w & 1;
  int l16 = lane & 15, quad = lane >> 4;
  int lrow = lane >> 2, lk = lane & 3;
  size_t rowB = (size_t)Dn * 2;
  int r0 = w * 32 + lrow;
  int ca = (lk - (r0 >> 1)) & 3;
  const char* gA0 = (const char*)refbf + (size_t)(rowBase + r0) * rowB + ca * 16;
  const char* gA1 = gA0 + 16 * rowB;
  const char* gB0 = (const char*)refbf + (size_t)(colBase + r0) * rowB + ca * 16;
  const char* gB1 = gB0 + 16 * rowB;
  char* lA = (char*)As + w * 2048;
  char* lB = (char*)Bs + w * 2048;

  f32x4 acc[4][4] = {};
  for (int k0 = 0; k0 < Dn; k0 += BK) {
    int koff = k0 * 2;
    GLOAD16(gA0 + koff, lA);
    GLOAD16(gA1 + koff, lA + 1024);
    GLOAD16(gB0 + koff, lB);
    GLOAD16(gB1 + koff, lB + 1024);
    __syncthreads();
    short8 af[4], bfr[4];
#pragma unroll
    for (int mi = 0; mi < 4; ++mi) {
      int row = wr * 64 + mi * 16 + l16;
      af[mi] = *(const short8*)&As[row * BK + ((quad + (row >> 1)) & 3) * 8];
    }
#pragma unroll
    for (int ni = 0; ni < 4; ++ni) {
      int row = wc * 64 + ni * 16 + l16;
      bfr[ni] = *(const short8*)&Bs[row * BK + ((quad + (row >> 1)) & 3) * 8];
    }
#pragma unroll
    for (int mi = 0; mi < 4; ++mi)
#pragma unroll
      for (int ni = 0; ni < 4; ++ni)
        acc[mi][ni] = __builtin_amdgcn_mfma_f32_16x16x32_bf16(
            af[mi], bfr[ni], acc[mi][ni], 0, 0, 0);
    __syncthreads();
  }

  float sqc[4];
  int labc[4];
#pragma unroll
  for (int ni = 0; ni < 4; ++ni) {
    int gcol = colBase + wc * 64 + ni * 16 + l16;
    sqc[ni] = sqb[gcol];
    labc[ni] = reflab[gcol];
  }
#pragma unroll
  for (int mi = 0; mi < 4; ++mi) {
    int lr0 = wr * 64 + mi * 16 + quad * 4;
#pragma unroll
    for (int r = 0; r < 4; ++r) {
      int lrl = lr0 + r;
      int grow = rowBase + lrl;
      float sqr = sqb[grow];
      int labr = reflab[grow];
      float ps = 0.f, pc = 0.f, ns = 0.f, nc = 0.f;
#pragma unroll
      for (int ni = 0; ni < 4; ++ni) {
        int gcol = colBase + wc * 64 + ni * 16 + l16;
        float dist = fmaxf(sqr + sqc[ni] - 2.0f * acc[mi][ni][r], 0.f);
        bool self = (gcol == grow);
        bool same = (labc[ni] == labr);
        if (same && !self && dist > 0.f) { ps += dist; pc += 1.f; }
        if (!same && !self && dist < 1.f) { ns += 1.f - dist; nc += 1.f; }
      }
#pragma unroll
      for (int off = 8; off; off >>= 1) {
        ps += __shfl_xor(ps, off);
        pc += __shfl_xor(pc, off);
        ns += __shfl_xor(ns, off);
        nc += __shfl_xor(nc, off);
      }
      if (l16 == 0) {
        f32x4 v = {ps, pc, ns, nc};
        redbuf4[wc * BM + lrl] = v;
      }
    }
  }
  __syncthreads();
  if (tid < BM) {
    f32x4 s = redbuf4[tid] + redbuf4[BM + tid];
    ((f32x4*)part)[(size_t)(rowBase + tid) * ntiles + jt] = s;
  }
}

// ---------- kernel 3: per-row fold + global sum (atomic + ticket) ----------
__global__ __launch_bounds__(256)
void reduce_final_kernel(const float* __restrict__ part,
                         float* __restrict__ facc, int* __restrict__ fcnt,
                         float* __restrict__ out, int Bn, int npart) {
  __shared__ float rsum[4];
  int tid = threadIdx.x, w = tid >> 6, lane = tid & 63;
  int row = blockIdx.x * 4 + w;
  const f32x4* part4 = (const f32x4*)part;
  float rl = 0.f;
  if (row < Bn) {
    f32x4 a = {0.f, 0.f, 0.f, 0.f};
    for (int j = lane; j < npart; j += 64)
      a += part4[(size_t)row * npart + j];
#pragma unroll
    for (int off = 32; off; off >>= 1) {
      a[0] += __shfl_xor(a[0], off);
      a[1] += __shfl_xor(a[1], off);
      a[2] += __shfl_xor(a[2], off);
      a[3] += __shfl_xor(a[3], off);
    }
    rl = a[0] / (a[1] + 1e-6f) + a[2] / (a[3] + 1e-6f);
  }
  if (lane == 0) rsum[w] = rl;
  __syncthreads();
  if (tid == 0) {
    float bs = rsum[0] + rsum[1] + rsum[2] + rsum[3];
    atomicAdd(facc, bs);
    __threadfence();
    int old = atomicAdd(fcnt, 1);
    if (old == (int)gridDim.x - 1) {
      __threadfence();
      float tot = atomicAdd(facc, 0.f);
      out[0] = tot / (float)Bn;
    }
  }
}

// ---------- host ----------
extern "C" void kernel_launch(void* const* d_in, const int* in_sizes, int n_in,
                              void* d_out, int out_size, void* d_ws, size_t ws_size,
                              hipStream_t stream) {
  const float* emb     = (const float*)d_in[0];
  const int*   labels  = (const int*)d_in[1];
  const float* emb_mem = (const float*)d_in[2];
  const int*   lbl_mem = (const int*)d_in[3];
  // d_in[4] (add_to_mem) does not affect the returned loss.

  int Bn = in_sizes[1];
  int Dn = in_sizes[0] / Bn;
  int Rn = in_sizes[3];
  int Mn = Bn + Rn;
  int mtiles = Bn / BM, ntiles = Mn / BN;

  char* ws = (char*)d_ws;
  unsigned char*  refq  = (unsigned char*)ws;                  // Mn*Dn fp8 (fast)
  unsigned short* refbf = (unsigned short*)ws;                 // Mn*Dn bf16 (generic)
  size_t off = (size_t)Mn * Dn * 2;                            // sized for bf16
  float* sqb    = (float*)(ws + off);                          // Mn
  int*   reflab = (int*)(ws + off + (size_t)Mn * 4);           // Mn
  float* part   = (float*)(ws + off + (size_t)Mn * 8);         // Bn*ntiles*4
  float* facc   = part + (size_t)Bn * ntiles * 4;              // 1
  int*   fcnt   = (int*)(facc + 1);                            // 1

  bool fast = (Dn == 512 && mtiles == 8 && ntiles == 256);
  if (fast) {
    prep_fp8_kernel<<<(Mn + 15) / 16, 256, 0, stream>>>(
        emb, labels, emb_mem, lbl_mem, refq, sqb, reflab, facc, fcnt, Bn, Dn, Mn);
    gemm512x2f8_kernel<<<1024, 256, 0, stream>>>(refq, sqb, reflab, part);
    reduce_final_kernel<<<(Bn + 3) / 4, 256, 0, stream>>>(
        part, facc, fcnt, (float*)d_out, Bn, 128);
  } else {
    prep2_kernel<<<(Mn + 3) / 4, 256, 0, stream>>>(
        emb, labels, emb_mem, lbl_mem, refbf, sqb, reflab, facc, fcnt, Bn, Dn, Mn);
    gemm_generic_kernel<<<mtiles * ntiles, 256, 0, stream>>>(
        refbf, sqb, reflab, part, Dn, mtiles, ntiles);
    reduce_final_kernel<<<(Bn + 3) / 4, 256, 0, stream>>>(
        part, facc, fcnt, (float*)d_out, Bn, ntiles);
  }
}

// Round 5
// 147.805 us; speedup vs baseline: 1.3203x; 1.0747x over previous
//
#include <hip/hip_runtime.h>
#include <hip/hip_fp8.h>

typedef __attribute__((ext_vector_type(8))) short short8;
typedef __attribute__((ext_vector_type(4))) float f32x4;
typedef __attribute__((ext_vector_type(2))) long long2v;

// async global->LDS, 16B per lane, dest = wave-uniform base + lane*16
#define GLOAD16(g, l)                                                        \
  __builtin_amdgcn_global_load_lds(                                          \
      (const __attribute__((address_space(1))) unsigned int*)(g),            \
      (__attribute__((address_space(3))) unsigned int*)(l), 16, 0, 0)

__device__ __forceinline__ unsigned short f2bf(float f) {
  union { float f; unsigned int u; } v;
  v.f = f;
  unsigned int u = v.u;
  u += 0x7FFFu + ((u >> 16) & 1u);  // round-to-nearest-even
  return (unsigned short)(u >> 16);
}

__device__ __forceinline__ short8 pack8(float4 a, float4 b) {
  short8 r;
  r[0] = (short)f2bf(a.x); r[1] = (short)f2bf(a.y);
  r[2] = (short)f2bf(a.z); r[3] = (short)f2bf(a.w);
  r[4] = (short)f2bf(b.x); r[5] = (short)f2bf(b.y);
  r[6] = (short)f2bf(b.z); r[7] = (short)f2bf(b.w);
  return r;
}

#define BM 128
#define BN 128
#define BK 32

// ---------- kernel 1a: prep for fp8 fast path (fp32 -> e4m3 + norms) -------
// Writes refq in GROUP-PERMUTED layout: within each 64B K-group g, byte
// position q*16 + cc*8 + b holds logical element k = g*64 + cc*32 + q*8 + b.
// This makes the GEMM's per-lane b128 LDS read deliver both K-chunk frags
// in one read. Conversion via HW v_cvt_pk_fp8_f32 (RNE, sat, e4m3fn).
__global__ __launch_bounds__(256)
void prep_fp8_kernel(const float* __restrict__ emb, const int* __restrict__ labels,
                     const float* __restrict__ emb_mem, const int* __restrict__ lbl_mem,
                     unsigned char* __restrict__ refq, float* __restrict__ sqb,
                     int* __restrict__ reflab, float* __restrict__ facc,
                     int* __restrict__ fcnt, int Bn, int Dn, int Mn) {
  if (blockIdx.x == 0 && threadIdx.x == 0) { *facc = 0.f; *fcnt = 0; }
  int wid = threadIdx.x >> 6, lane = threadIdx.x & 63;
  int row0 = blockIdx.x * 16 + wid * 4;
  // lane's 8 floats: f0 = lane*8; g = lane>>3, cc = (lane>>2)&1, q = lane&3
  int dsto = ((lane >> 3) << 6) + ((lane & 3) << 4) + (((lane >> 2) & 1) << 3);
#pragma unroll
  for (int rr = 0; rr < 4; ++rr) {
    int row = row0 + rr;
    if (row >= Mn) continue;
    const float* src = (row < Bn) ? (emb + (size_t)row * Dn)
                                  : (emb_mem + (size_t)(row - Bn) * Dn);
    unsigned char* dst = refq + (size_t)row * Dn;
    float s = 0.f;
    for (int c0 = lane * 8; c0 < Dn; c0 += 64 * 8) {
      float4 v0 = ((const float4*)(src + c0))[0];
      float4 v1 = ((const float4*)(src + c0))[1];
      s += v0.x * v0.x + v0.y * v0.y + v0.z * v0.z + v0.w * v0.w;
      s += v1.x * v1.x + v1.y * v1.y + v1.z * v1.z + v1.w * v1.w;
      int w0 = 0, w1 = 0;
      w0 = __builtin_amdgcn_cvt_pk_fp8_f32(v0.x, v0.y, w0, false);
      w0 = __builtin_amdgcn_cvt_pk_fp8_f32(v0.z, v0.w, w0, true);
      w1 = __builtin_amdgcn_cvt_pk_fp8_f32(v1.x, v1.y, w1, false);
      w1 = __builtin_amdgcn_cvt_pk_fp8_f32(v1.z, v1.w, w1, true);
      int2 p = {w0, w1};
      *(int2*)(dst + (c0 & ~511) + dsto) = p;  // Dn=512: c0&~511 == 0
    }
#pragma unroll
    for (int off = 32; off; off >>= 1) s += __shfl_xor(s, off);
    if (lane == 0) {
      sqb[row] = s;
      reflab[row] = (row < Bn) ? labels[row] : lbl_mem[row - Bn];
    }
  }
}

// ---------- kernel 2a: fp8 GEMM 128x256, BK=64 2-phase dbuf ---------------
// T3-minimum recipe: STAGE(t+1) -> ds_read(t) -> MFMA -> syncthreads.
// One barrier per 64B K-tile (8 total vs 32), stage latency hidden under
// MFMA. AGPR-backed acc via non-scaled fp8 MFMA (VGPR 88 proven; mfma_scale
// gets no AGPR allocation -> dead end, rounds 1-3).
// LDS: 2 x (A 8KB + B 16KB) = 48KB; epilogue red4 aliases first 32KB.
// refq is group-permuted (see prep): lane (quad,l16) b128-reads its frags
// for both K-chunks at row*64 + ((quad ^ (row&3))<<4); XOR applied on the
// staging global source too (both-sides-or-neither) -> uniform bank spread.
__global__ __launch_bounds__(256, 2)
void gemm512x2f8_kernel(const unsigned char* __restrict__ refq,
                        const float* __restrict__ sqb,
                        const int* __restrict__ reflab,
                        float* __restrict__ part) {
  __shared__ __align__(16) char smem[49152];
  f32x4* red4 = (f32x4*)smem;  // [2][128][8] f32x4 = 32KB (aliases staging)

  const int npart = 128;               // j-pairs
  int bid = blockIdx.x;                // 1024 blocks
  int c = bid & 7, g = bid >> 3;       // XCD-sliced (validated)
  int jp = c * 16 + (g >> 3);          // j-pair index [0,128)
  int it = g & 7;
  int rowBase = it * BM, colBase = jp * 256;

  int tid = threadIdx.x, lane = tid & 63, w = tid >> 6;
  int wr = w >> 1, wc = w & 1;         // 2x2 waves; each 64 rows x 128 cols
  int l16 = lane & 15, quad = lane >> 4;

  // staging: lane -> row lane>>2 (16 rows/GLOAD), slot lane&3 (4x16B/row)
  int srow = lane >> 2, sslot = lane & 3;
  const char* gA = (const char*)refq + (size_t)(rowBase + w * 32 + srow) * 512
                   + ((sslot ^ (srow & 3)) << 4);
  const char* gB = (const char*)refq + (size_t)(colBase + w * 64 + srow) * 512
                   + ((sslot ^ (srow & 3)) << 4);

#define STAGE(t, buf)                                                       \
  { char* As_ = smem + (buf) * 24576; char* Bs_ = As_ + 8192;               \
    int ko = (t) * 64;                                                      \
    GLOAD16(gA + ko,         As_ + w * 2048);                               \
    GLOAD16(gA + ko + 8192,  As_ + w * 2048 + 1024);                        \
    GLOAD16(gB + ko,         Bs_ + w * 4096);                               \
    GLOAD16(gB + ko + 8192,  Bs_ + w * 4096 + 1024);                        \
    GLOAD16(gB + ko + 16384, Bs_ + w * 4096 + 2048);                        \
    GLOAD16(gB + ko + 24576, Bs_ + w * 4096 + 3072); }

  f32x4 acc[4][8] = {};
  STAGE(0, 0);
  __syncthreads();  // drains vmcnt(0): buf0 ready

  for (int t = 0; t < 8; ++t) {
    int cur = t & 1;
    if (t < 7) STAGE(t + 1, cur ^ 1);  // issue next tile BEFORE compute
    const char* As = smem + cur * 24576;
    const char* Bs = As + 8192;
    long2v af[4], bf[8];
#pragma unroll
    for (int mi = 0; mi < 4; ++mi) {
      int r = wr * 64 + mi * 16 + l16;
      af[mi] = *(const long2v*)(As + r * 64 + ((quad ^ (l16 & 3)) << 4));
    }
#pragma unroll
    for (int ni = 0; ni < 8; ++ni) {
      int r = wc * 128 + ni * 16 + l16;
      bf[ni] = *(const long2v*)(Bs + r * 64 + ((quad ^ (l16 & 3)) << 4));
    }
    __builtin_amdgcn_s_setprio(1);
#pragma unroll
    for (int mi = 0; mi < 4; ++mi)
#pragma unroll
      for (int ni = 0; ni < 8; ++ni) {
        acc[mi][ni] = __builtin_amdgcn_mfma_f32_16x16x32_fp8_fp8(
            af[mi][0], bf[ni][0], acc[mi][ni], 0, 0, 0);
        acc[mi][ni] = __builtin_amdgcn_mfma_f32_16x16x32_fp8_fp8(
            af[mi][1], bf[ni][1], acc[mi][ni], 0, 0, 0);
      }
    __builtin_amdgcn_s_setprio(0);
    __syncthreads();  // reads of cur done; stage for t+1 landed
  }
#undef STAGE

  // ---- epilogue (validated): packed counters, 1 shfl, LDS fold -----------
  float sqc[8];
  int labc[8];
#pragma unroll
  for (int ni = 0; ni < 8; ++ni) {
    int gcol = colBase + wc * 128 + ni * 16 + l16;
    sqc[ni] = sqb[gcol];
    labc[ni] = reflab[gcol];
  }
#pragma unroll
  for (int mi = 0; mi < 4; ++mi) {
    int lr0 = wr * 64 + mi * 16 + quad * 4;
#pragma unroll
    for (int r = 0; r < 4; ++r) {
      int lrl = lr0 + r;
      int grow = rowBase + lrl;
      float sqr = sqb[grow];
      int labr = reflab[grow];
      float ps = 0.f, ns = 0.f, cpk = 0.f;  // cpk = pos_cnt + 512*neg_cnt
#pragma unroll
      for (int ni = 0; ni < 8; ++ni) {
        int gcol = colBase + wc * 128 + ni * 16 + l16;
        float dist = fmaxf(sqr + sqc[ni] - 2.0f * acc[mi][ni][r], 0.f);
        bool self = (gcol == grow);  // idx_ref[j]!=i reduces to j!=i
        bool same = (labc[ni] == labr);
        if (same && !self && dist > 0.f) { ps += dist; cpk += 1.f; }
        if (!same && !self && dist < 1.f) { ns += 1.f - dist; cpk += 512.f; }
      }
      ps += __shfl_xor(ps, 8);
      ns += __shfl_xor(ns, 8);
      cpk += __shfl_xor(cpk, 8);
      if (l16 < 8) {
        f32x4 v = {ps, ns, cpk, 0.f};
        red4[(wc * BM + lrl) * 8 + l16] = v;
      }
    }
  }
  __syncthreads();
  if (tid < BM) {
    f32x4 s = {0.f, 0.f, 0.f, 0.f};
#pragma unroll
    for (int c2 = 0; c2 < 2; ++c2)
#pragma unroll
      for (int k = 0; k < 8; ++k)  // (k+tid)&7: lanes sweep all 32 banks
        s += red4[(c2 * BM + tid) * 8 + ((k + tid) & 7)];
    float nc = floorf(s[2] * (1.0f / 512.0f));
    float pc = s[2] - 512.f * nc;
    f32x4 o = {s[0], pc, s[1], nc};
    ((f32x4*)part)[(size_t)(rowBase + tid) * npart + jp] = o;  // [row][jp]
  }
}

// ---------- fallback path (generic shapes): bf16 prep + generic GEMM -------
__global__ __launch_bounds__(256)
void prep2_kernel(const float* __restrict__ emb, const int* __restrict__ labels,
                  const float* __restrict__ emb_mem, const int* __restrict__ lbl_mem,
                  unsigned short* __restrict__ refbf, float* __restrict__ sqb,
                  int* __restrict__ reflab, float* __restrict__ facc,
                  int* __restrict__ fcnt, int Bn, int Dn, int Mn) {
  if (blockIdx.x == 0 && threadIdx.x == 0) { *facc = 0.f; *fcnt = 0; }
  int wid = threadIdx.x >> 6, lane = threadIdx.x & 63;
  int row = blockIdx.x * 4 + wid;
  if (row >= Mn) return;
  const float* src = (row < Bn) ? (emb + (size_t)row * Dn)
                                : (emb_mem + (size_t)(row - Bn) * Dn);
  unsigned short* dst = refbf + (size_t)row * Dn;
  float s = 0.f;
  for (int c0 = lane * 8; c0 < Dn; c0 += 64 * 8) {
    float4 v0 = ((const float4*)(src + c0))[0];
    float4 v1 = ((const float4*)(src + c0))[1];
    s += v0.x * v0.x + v0.y * v0.y + v0.z * v0.z + v0.w * v0.w;
    s += v1.x * v1.x + v1.y * v1.y + v1.z * v1.z + v1.w * v1.w;
    *(short8*)(dst + c0) = pack8(v0, v1);
  }
#pragma unroll
  for (int off = 32; off; off >>= 1) s += __shfl_xor(s, off);
  if (lane == 0) {
    sqb[row] = s;
    reflab[row] = (row < Bn) ? labels[row] : lbl_mem[row - Bn];
  }
}

__global__ __launch_bounds__(256)
void gemm_generic_kernel(const unsigned short* __restrict__ refbf,
                         const float* __restrict__ sqb,
                         const int* __restrict__ reflab,
                         float* __restrict__ part,
                         int Dn, int mtiles, int ntiles) {
  __shared__ unsigned short As[BM * BK];
  __shared__ unsigned short Bs[BN * BK];
  __shared__ f32x4 redbuf4[2 * BM];

  int bid = blockIdx.x;
  int it = bid % mtiles, jt = bid / mtiles;
  int rowBase = it * BM, colBase = jt * BN;
  int tid = threadIdx.x, lane = tid & 63, w = tid >> 6;
  int wr = w >> 1, wc = w & 1;
  int l16 = lane & 15, quad = lane >> 4;
  int lrow = lane >> 2, lk = lane & 3;
  size_t rowB = (size_t)Dn * 2;
  int r0 = w * 32 + lrow;
  int ca = (lk - (r0 >> 1)) & 3;
  const char* gA0 = (const char*)refbf + (size_t)(rowBase + r0) * rowB + ca * 16;
  const char* gA1 = gA0 + 16 * rowB;
  const char* gB0 = (const char*)refbf + (size_t)(colBase + r0) * rowB + ca * 16;
  const char* gB1 = gB0 + 16 * rowB;
  char* lA = (char*)As + w * 2048;
  char* lB = (char*)Bs + w * 2048;

  f32x4 acc[4][4] = {};
  for (int k0 = 0; k0 < Dn; k0 += BK) {
    int koff = k0 * 2;
    GLOAD16(gA0 + koff, lA);
    GLOAD16(gA1 + koff, lA + 1024);
    GLOAD16(gB0 + koff, lB);
    GLOAD16(gB1 + koff, lB + 1024);
    __syncthreads();
    short8 af[4], bfr[4];
#pragma unroll
    for (int mi = 0; mi < 4; ++mi) {
      int row = wr * 64 + mi * 16 + l16;
      af[mi] = *(const short8*)&As[row * BK + ((quad + (row >> 1)) & 3) * 8];
    }
#pragma unroll
    for (int ni = 0; ni < 4; ++ni) {
      int row = wc * 64 + ni * 16 + l16;
      bfr[ni] = *(const short8*)&Bs[row * BK + ((quad + (row >> 1)) & 3) * 8];
    }
#pragma unroll
    for (int mi = 0; mi < 4; ++mi)
#pragma unroll
      for (int ni = 0; ni < 4; ++ni)
        acc[mi][ni] = __builtin_amdgcn_mfma_f32_16x16x32_bf16(
            af[mi], bfr[ni], acc[mi][ni], 0, 0, 0);
    __syncthreads();
  }

  float sqc[4];
  int labc[4];
#pragma unroll
  for (int ni = 0; ni < 4; ++ni) {
    int gcol = colBase + wc * 64 + ni * 16 + l16;
    sqc[ni] = sqb[gcol];
    labc[ni] = reflab[gcol];
  }
#pragma unroll
  for (int mi = 0; mi < 4; ++mi) {
    int lr0 = wr * 64 + mi * 16 + quad * 4;
#pragma unroll
    for (int r = 0; r < 4; ++r) {
      int lrl = lr0 + r;
      int grow = rowBase + lrl;
      float sqr = sqb[grow];
      int labr = reflab[grow];
      float ps = 0.f, pc = 0.f, ns = 0.f, nc = 0.f;
#pragma unroll
      for (int ni = 0; ni < 4; ++ni) {
        int gcol = colBase + wc * 64 + ni * 16 + l16;
        float dist = fmaxf(sqr + sqc[ni] - 2.0f * acc[mi][ni][r], 0.f);
        bool self = (gcol == grow);
        bool same = (labc[ni] == labr);
        if (same && !self && dist > 0.f) { ps += dist; pc += 1.f; }
        if (!same && !self && dist < 1.f) { ns += 1.f - dist; nc += 1.f; }
      }
#pragma unroll
      for (int off = 8; off; off >>= 1) {
        ps += __shfl_xor(ps, off);
        pc += __shfl_xor(pc, off);
        ns += __shfl_xor(ns, off);
        nc += __shfl_xor(nc, off);
      }
      if (l16 == 0) {
        f32x4 v = {ps, pc, ns, nc};
        redbuf4[wc * BM + lrl] = v;
      }
    }
  }
  __syncthreads();
  if (tid < BM) {
    f32x4 s = redbuf4[tid] + redbuf4[BM + tid];
    ((f32x4*)part)[(size_t)(rowBase + tid) * ntiles + jt] = s;
  }
}

// ---------- kernel 3: per-row fold + global sum (atomic + ticket) ----------
__global__ __launch_bounds__(256)
void reduce_final_kernel(const float* __restrict__ part,
                         float* __restrict__ facc, int* __restrict__ fcnt,
                         float* __restrict__ out, int Bn, int npart) {
  __shared__ float rsum[4];
  int tid = threadIdx.x, w = tid >> 6, lane = tid & 63;
  int row = blockIdx.x * 4 + w;
  const f32x4* part4 = (const f32x4*)part;
  float rl = 0.f;
  if (row < Bn) {
    f32x4 a = {0.f, 0.f, 0.f, 0.f};
    for (int j = lane; j < npart; j += 64)
      a += part4[(size_t)row * npart + j];
#pragma unroll
    for (int off = 32; off; off >>= 1) {
      a[0] += __shfl_xor(a[0], off);
      a[1] += __shfl_xor(a[1], off);
      a[2] += __shfl_xor(a[2], off);
      a[3] += __shfl_xor(a[3], off);
    }
    rl = a[0] / (a[1] + 1e-6f) + a[2] / (a[3] + 1e-6f);
  }
  if (lane == 0) rsum[w] = rl;
  __syncthreads();
  if (tid == 0) {
    float bs = rsum[0] + rsum[1] + rsum[2] + rsum[3];
    atomicAdd(facc, bs);
    __threadfence();
    int old = atomicAdd(fcnt, 1);
    if (old == (int)gridDim.x - 1) {
      __threadfence();
      float tot = atomicAdd(facc, 0.f);
      out[0] = tot / (float)Bn;
    }
  }
}

// ---------- host ----------
extern "C" void kernel_launch(void* const* d_in, const int* in_sizes, int n_in,
                              void* d_out, int out_size, void* d_ws, size_t ws_size,
                              hipStream_t stream) {
  const float* emb     = (const float*)d_in[0];
  const int*   labels  = (const int*)d_in[1];
  const float* emb_mem = (const float*)d_in[2];
  const int*   lbl_mem = (const int*)d_in[3];
  // d_in[4] (add_to_mem) does not affect the returned loss.

  int Bn = in_sizes[1];
  int Dn = in_sizes[0] / Bn;
  int Rn = in_sizes[3];
  int Mn = Bn + Rn;
  int mtiles = Bn / BM, ntiles = Mn / BN;

  char* ws = (char*)d_ws;
  unsigned char*  refq  = (unsigned char*)ws;                  // Mn*Dn fp8 (fast)
  unsigned short* refbf = (unsigned short*)ws;                 // Mn*Dn bf16 (generic)
  size_t off = (size_t)Mn * Dn * 2;                            // sized for bf16
  float* sqb    = (float*)(ws + off);                          // Mn
  int*   reflab = (int*)(ws + off + (size_t)Mn * 4);           // Mn
  float* part   = (float*)(ws + off + (size_t)Mn * 8);         // Bn*ntiles*4
  float* facc   = part + (size_t)Bn * ntiles * 4;              // 1
  int*   fcnt   = (int*)(facc + 1);                            // 1

  bool fast = (Dn == 512 && mtiles == 8 && ntiles == 256);
  if (fast) {
    prep_fp8_kernel<<<(Mn + 15) / 16, 256, 0, stream>>>(
        emb, labels, emb_mem, lbl_mem, refq, sqb, reflab, facc, fcnt, Bn, Dn, Mn);
    gemm512x2f8_kernel<<<1024, 256, 0, stream>>>(refq, sqb, reflab, part);
    reduce_final_kernel<<<(Bn + 3) / 4, 256, 0, stream>>>(
        part, facc, fcnt, (float*)d_out, Bn, 128);
  } else {
    prep2_kernel<<<(Mn + 3) / 4, 256, 0, stream>>>(
        emb, labels, emb_mem, lbl_mem, refbf, sqb, reflab, facc, fcnt, Bn, Dn, Mn);
    gemm_generic_kernel<<<mtiles * ntiles, 256, 0, stream>>>(
        refbf, sqb, reflab, part, Dn, mtiles, ntiles);
    reduce_final_kernel<<<(Bn + 3) / 4, 256, 0, stream>>>(
        part, facc, fcnt, (float*)d_out, Bn, ntiles);
  }
}